// Round 1
// baseline (584.296 us; speedup 1.0000x reference)
//
#include <hip/hip_runtime.h>

// PairDistanceLoss: loss_i = (sum_{y=1} exp(x)) * (sum_{y=0} exp(-x)) / (ni*(C-ni))
// output = mean_i loss_i  (single fp32 scalar)
// N=16384 rows, C=4096 cols. Memory-bound: 512 MB read -> ~81 us floor @ 6.3 TB/s.

#define C_DIM 4096
#define BLOCK 256

__global__ __launch_bounds__(BLOCK) void pdl_kernel(const float* __restrict__ x,
                                                    const int* __restrict__ y,
                                                    float* __restrict__ out,
                                                    float inv_n) {
    const int row = blockIdx.x;
    const size_t base = (size_t)row * C_DIM;
    const float4* __restrict__ x4 = (const float4*)(x + base);
    const int4*  __restrict__ y4 = (const int4*)(y + base);

    float pos = 0.0f, neg = 0.0f;
    int cnt = 0;

    // C/4 = 1024 float4 groups, 256 threads -> 4 iterations, fully coalesced 16B/lane
#pragma unroll
    for (int it = 0; it < (C_DIM / 4) / BLOCK; ++it) {
        const int i = threadIdx.x + it * BLOCK;
        const float4 xv = x4[i];
        const int4  yv = y4[i];

        {
            const float e = __expf(yv.x ? xv.x : -xv.x);
            pos += yv.x ? e : 0.0f;  neg += yv.x ? 0.0f : e;  cnt += yv.x;
        }
        {
            const float e = __expf(yv.y ? xv.y : -xv.y);
            pos += yv.y ? e : 0.0f;  neg += yv.y ? 0.0f : e;  cnt += yv.y;
        }
        {
            const float e = __expf(yv.z ? xv.z : -xv.z);
            pos += yv.z ? e : 0.0f;  neg += yv.z ? 0.0f : e;  cnt += yv.z;
        }
        {
            const float e = __expf(yv.w ? xv.w : -xv.w);
            pos += yv.w ? e : 0.0f;  neg += yv.w ? 0.0f : e;  cnt += yv.w;
        }
    }

    // wave-64 butterfly reduction
#pragma unroll
    for (int off = 32; off >= 1; off >>= 1) {
        pos += __shfl_down(pos, off, 64);
        neg += __shfl_down(neg, off, 64);
        cnt += __shfl_down(cnt, off, 64);
    }

    __shared__ float sp[BLOCK / 64];
    __shared__ float sn[BLOCK / 64];
    __shared__ int   sc[BLOCK / 64];

    const int lane = threadIdx.x & 63;
    const int wave = threadIdx.x >> 6;
    if (lane == 0) { sp[wave] = pos; sn[wave] = neg; sc[wave] = cnt; }
    __syncthreads();

    if (threadIdx.x == 0) {
        float P = 0.0f, Ng = 0.0f;
        int ni = 0;
#pragma unroll
        for (int w = 0; w < BLOCK / 64; ++w) { P += sp[w]; Ng += sn[w]; ni += sc[w]; }
        const float denom = (float)ni * (float)(C_DIM - ni);
        const float loss = (P * Ng) / denom;
        atomicAdd(out, loss * inv_n);
    }
}

extern "C" void kernel_launch(void* const* d_in, const int* in_sizes, int n_in,
                              void* d_out, int out_size, void* d_ws, size_t ws_size,
                              hipStream_t stream) {
    const float* x = (const float*)d_in[0];
    const int*   y = (const int*)d_in[1];
    float* out = (float*)d_out;

    const int n_rows = in_sizes[0] / C_DIM;  // 16384

    // d_out is poisoned to 0xAA before every call -> zero it (graph-capturable)
    hipMemsetAsync(d_out, 0, sizeof(float), stream);

    pdl_kernel<<<n_rows, BLOCK, 0, stream>>>(x, y, out, 1.0f / (float)n_rows);
}

// Round 2
// 497.047 us; speedup vs baseline: 1.1755x; 1.1755x over previous
//
#include <hip/hip_runtime.h>

// PairDistanceLoss: loss_i = (sum_{y=1} exp(x)) * (sum_{y=0} exp(-x)) / (ni*(C-ni))
// output = mean_i loss_i (fp32 scalar). N=16384 rows, C=4096 cols.
//
// R1 post-mortem: 16384 same-address atomicAdds serialized (~34 cyc each = 230us);
// VGPR=20 meant zero load ILP. Fix: block partials -> d_ws -> tiny reduce kernel;
// wave-per-row mapping with 8 batched 16B loads in flight per lane.

#define C_DIM 4096
#define BLOCK 256
#define NBLK  2048
#define WAVES_PER_BLOCK (BLOCK / 64)

__global__ __launch_bounds__(BLOCK) void pdl_rows(const float* __restrict__ x,
                                                  const int* __restrict__ y,
                                                  float* __restrict__ partial,
                                                  int rows_per_wave) {
    const int lane = threadIdx.x & 63;
    const int wave = threadIdx.x >> 6;
    const int gwave = blockIdx.x * WAVES_PER_BLOCK + wave;

    float wacc = 0.0f;  // meaningful on lane 0 only

    for (int r = 0; r < rows_per_wave; ++r) {
        const int row = gwave * rows_per_wave + r;
        const float4* __restrict__ x4 = (const float4*)(x + (size_t)row * C_DIM);
        const int4*  __restrict__ y4 = (const int4*)(y + (size_t)row * C_DIM);

        float pos = 0.0f, neg = 0.0f;
        int cnt = 0;

        // 4096 elems / 64 lanes / 4-per-float4 = 16 vector loads per lane;
        // batch 4 x-loads + 4 y-loads per chunk so 8 are in flight (MLP).
#pragma unroll
        for (int chunk = 0; chunk < 4; ++chunk) {
            float4 xv[4];
            int4  yv[4];
#pragma unroll
            for (int u = 0; u < 4; ++u) {
                const int i = lane + (chunk * 4 + u) * 64;
                xv[u] = x4[i];
                yv[u] = y4[i];
            }
#pragma unroll
            for (int u = 0; u < 4; ++u) {
                { const float e = __expf(yv[u].x ? xv[u].x : -xv[u].x);
                  pos += yv[u].x ? e : 0.0f; neg += yv[u].x ? 0.0f : e; cnt += yv[u].x; }
                { const float e = __expf(yv[u].y ? xv[u].y : -xv[u].y);
                  pos += yv[u].y ? e : 0.0f; neg += yv[u].y ? 0.0f : e; cnt += yv[u].y; }
                { const float e = __expf(yv[u].z ? xv[u].z : -xv[u].z);
                  pos += yv[u].z ? e : 0.0f; neg += yv[u].z ? 0.0f : e; cnt += yv[u].z; }
                { const float e = __expf(yv[u].w ? xv[u].w : -xv[u].w);
                  pos += yv[u].w ? e : 0.0f; neg += yv[u].w ? 0.0f : e; cnt += yv[u].w; }
            }
        }

        // wave-64 reduction: lane 0 ends with the row totals
#pragma unroll
        for (int off = 32; off >= 1; off >>= 1) {
            pos += __shfl_down(pos, off, 64);
            neg += __shfl_down(neg, off, 64);
            cnt += __shfl_down(cnt, off, 64);
        }
        if (lane == 0) {
            const float denom = (float)cnt * (float)(C_DIM - cnt);
            wacc += (pos * neg) / denom;
        }
    }

    __shared__ float sacc[WAVES_PER_BLOCK];
    if (lane == 0) sacc[wave] = wacc;
    __syncthreads();
    if (threadIdx.x == 0) {
        float b = 0.0f;
#pragma unroll
        for (int w = 0; w < WAVES_PER_BLOCK; ++w) b += sacc[w];
        partial[blockIdx.x] = b;  // plain store, no atomic
    }
}

__global__ __launch_bounds__(BLOCK) void pdl_reduce(const float* __restrict__ partial,
                                                    float* __restrict__ out,
                                                    float inv_n) {
    float s = 0.0f;
    for (int i = threadIdx.x; i < NBLK; i += BLOCK) s += partial[i];
#pragma unroll
    for (int off = 32; off >= 1; off >>= 1) s += __shfl_down(s, off, 64);
    __shared__ float sw[WAVES_PER_BLOCK];
    const int lane = threadIdx.x & 63;
    const int wave = threadIdx.x >> 6;
    if (lane == 0) sw[wave] = s;
    __syncthreads();
    if (threadIdx.x == 0) {
        float t = 0.0f;
#pragma unroll
        for (int w = 0; w < WAVES_PER_BLOCK; ++w) t += sw[w];
        out[0] = t * inv_n;
    }
}

extern "C" void kernel_launch(void* const* d_in, const int* in_sizes, int n_in,
                              void* d_out, int out_size, void* d_ws, size_t ws_size,
                              hipStream_t stream) {
    const float* x = (const float*)d_in[0];
    const int*   y = (const int*)d_in[1];
    float* out = (float*)d_out;
    float* partial = (float*)d_ws;  // NBLK floats; written unconditionally each call

    const int n_rows = in_sizes[0] / C_DIM;                       // 16384
    const int rows_per_wave = n_rows / (NBLK * WAVES_PER_BLOCK);  // 2

    pdl_rows<<<NBLK, BLOCK, 0, stream>>>(x, y, partial, rows_per_wave);
    pdl_reduce<<<1, BLOCK, 0, stream>>>(partial, out, 1.0f / (float)n_rows);
}